// Round 16
// baseline (36.287 us; speedup 1.0000x reference)
//
#include <hip/hip_runtime.h>

// SSIM loss: predict/gt (32,1,512,512) f32, 11-tap separable gaussian (sigma=1.5),
// VALID padding -> 502x502 per image, loss = 1 - mean(ssim_map).
//
// Round 16: wave-autonomous MFMA, zero-LDS datapath. Each wave loads its
// vertical A-fragments straight from global (48 independent dword loads,
// 4x64B segments each), converts to f16, runs the r12-verified MFMA chain:
// vertical (A_data x B_wgt banded) -> in-register f16 V -> horizontal
// (A_vreg x B_wgt) -> SSIM epilogue. No barriers, no staging, no transposes.
// Wave = 16 out rows x 32 out cols; block = 4 waves (adjacent col chunks).

typedef _Float16 f16;
typedef __attribute__((ext_vector_type(4))) _Float16 f16x4;
typedef __attribute__((ext_vector_type(8))) _Float16 f16x8;
typedef __attribute__((ext_vector_type(4))) float f32x4;

constexpr int WIN = 11;
constexpr int H = 512, W = 512, NIMG = 32;
constexpr int OH = H - WIN + 1, OW = W - WIN + 1;  // 502
constexpr int NSTRIP = 32;   // ceil(502/16) row strips
constexpr int NCB = 4;       // col blocks of 128 (4 waves x 32)
constexpr int NBLK = NIMG * NSTRIP * NCB;  // 4096
constexpr float C1 = 0.009801f;   // (0.01*9.9)^2
constexpr float C2 = 0.088209f;   // (0.03*9.9)^2
constexpr double TOTAL = (double)NIMG * (double)OH * (double)OW;

__device__ constexpr float WGT[WIN] = {
    0.0010285f, 0.0075988f, 0.0360008f, 0.1093607f, 0.2130054f,
    0.2660118f,
    0.2130054f, 0.1093607f, 0.0360008f, 0.0075988f, 0.0010285f};

// ---- init: banded weight fragments, one f16x8 per lane (1KB table in ws)
__global__ void init_kernel(f16* __restrict__ wtab) {
    const int lane = threadIdx.x;   // 64 threads
    const int r = lane & 15;
    const int q = lane >> 4;
    f16x8 w;
#pragma unroll
    for (int e = 0; e < 8; ++e) {
        const int k = (e < 4) ? (4 * q + e) : (16 + 4 * q + (e - 4));
        const int d = k - r;
        w[e] = (d >= 0 && d <= 10) ? (f16)WGT[d] : (f16)0.f;
    }
    *(f16x8*)(wtab + 8 * lane) = w;
}

__global__ __launch_bounds__(256, 4) void ssim_mfma_kernel(const float* __restrict__ P,
                                                           const float* __restrict__ G,
                                                           const f16* __restrict__ wtab,
                                                           float* __restrict__ blocksum) {
    __shared__ float wsum[4];

    const int tid = threadIdx.x;
    const int lane = tid & 63;
    const int wid = tid >> 6;
    const int r = lane & 15;         // A row / B col / D col
    const int q = lane >> 4;         // k-group; D rows 4q..4q+3

    const int bid = blockIdx.x;
    const int img = bid / (NSTRIP * NCB);
    const int rem = bid % (NSTRIP * NCB);
    const int strip = rem / NCB;
    const int cbk = rem % NCB;
    const int R0 = strip * 16;
    const int CW = cbk * 128 + wid * 32;   // this wave's first output col

    const f16x8 wfrag = *(const f16x8*)(wtab + 8 * lane);

    const float* p = P + (size_t)img * H * W;
    const float* g = G + (size_t)img * H * W;

    // ---- direct global loads of vertical A-fragments: 3 colgroups x 2 arrays
    // x 8 k-elems. Lane(r,q), elem (h,e): X[min(R0+16h+4q+e,511)][min(CW+16cg+r,511)]
    float fp[3][8], fg[3][8];
    int coff[3];
#pragma unroll
    for (int cg = 0; cg < 3; ++cg)
        coff[cg] = min(CW + 16 * cg + r, W - 1);
#pragma unroll
    for (int h = 0; h < 2; ++h) {
#pragma unroll
        for (int e = 0; e < 4; ++e) {
            const int row = min(R0 + 16 * h + 4 * q + e, H - 1);
            const size_t rbase = (size_t)row * W;
#pragma unroll
            for (int cg = 0; cg < 3; ++cg) {
                fp[cg][4 * h + e] = p[rbase + coff[cg]];
                fg[cg][4 * h + e] = g[rbase + coff[cg]];
            }
        }
    }

    const f32x4 zero = {0.f, 0.f, 0.f, 0.f};

    // ---- vertical MFMA -> f16 V fragments in registers
    f16x4 v16[3][5];
#pragma unroll
    for (int cg = 0; cg < 3; ++cg) {
        f16x8 ap, ag;
#pragma unroll
        for (int e = 0; e < 8; ++e) {
            ap[e] = (f16)fp[cg][e];
            ag[e] = (f16)fg[cg][e];
        }
        const f16x8 app = ap * ap;
        const f16x8 agg = ag * ag;
        const f16x8 apg = ap * ag;
        const f32x4 D0 = __builtin_amdgcn_mfma_f32_16x16x32_f16(ap,  wfrag, zero, 0, 0, 0);
        const f32x4 D1 = __builtin_amdgcn_mfma_f32_16x16x32_f16(ag,  wfrag, zero, 0, 0, 0);
        const f32x4 D2 = __builtin_amdgcn_mfma_f32_16x16x32_f16(app, wfrag, zero, 0, 0, 0);
        const f32x4 D3 = __builtin_amdgcn_mfma_f32_16x16x32_f16(agg, wfrag, zero, 0, 0, 0);
        const f32x4 D4 = __builtin_amdgcn_mfma_f32_16x16x32_f16(apg, wfrag, zero, 0, 0, 0);
#pragma unroll
        for (int m = 0; m < 4; ++m) {
            v16[cg][0][m] = (f16)D0[m];
            v16[cg][1][m] = (f16)D1[m];
            v16[cg][2][m] = (f16)D2[m];
            v16[cg][3][m] = (f16)D3[m];
            v16[cg][4][m] = (f16)D4[m];
        }
    }

    // ---- horizontal MFMA + SSIM epilogue (2 outgroups per wave)
    float lsum = 0.f;
#pragma unroll
    for (int j = 0; j < 2; ++j) {
        f32x4 acc[5];
#pragma unroll
        for (int ch = 0; ch < 5; ++ch) {
            const f16x8 afrag = __builtin_shufflevector(v16[j][ch], v16[j + 1][ch],
                                                        0, 1, 2, 3, 4, 5, 6, 7);
            acc[ch] = __builtin_amdgcn_mfma_f32_16x16x32_f16(afrag, wfrag, zero, 0, 0, 0);
        }
        const int ocol = CW + 16 * j + r;
#pragma unroll
        for (int m = 0; m < 4; ++m) {
            const int orow = R0 + 4 * q + m;
            const bool ok = (orow < OH) && (ocol < OW);
            const float m1 = acc[0][m], m2 = acc[1][m];
            const float e11 = acc[2][m], e22 = acc[3][m], e12 = acc[4][m];
            const float mu11 = m1 * m1, mu22 = m2 * m2, mu12 = m1 * m2;
            const float s11 = e11 - mu11, s22 = e22 - mu22, s12 = e12 - mu12;
            const float num = (2.f * mu12 + C1) * (2.f * s12 + C2);
            const float den = (mu11 + mu22 + C1) * (s11 + s22 + C2);
            lsum += ok ? __fdividef(num, den) : 0.f;
        }
    }

    // ---- block reduction (single trivial barrier at the end)
#pragma unroll
    for (int off = 32; off > 0; off >>= 1)
        lsum += __shfl_down(lsum, off, 64);
    if (lane == 0) wsum[wid] = lsum;
    __syncthreads();
    if (tid == 0)
        blocksum[bid] = (wsum[0] + wsum[1]) + (wsum[2] + wsum[3]);
}

// one-block reduction of 4096 block sums (1024 float4, latency-overlapped)
__global__ __launch_bounds__(256) void reduce_kernel(const float4* __restrict__ bs4,
                                                     float* __restrict__ out) {
    const int tid = threadIdx.x;
    const float4 a0 = bs4[tid];
    const float4 a1 = bs4[tid + 256];
    const float4 a2 = bs4[tid + 512];
    const float4 a3 = bs4[tid + 768];
    float s = ((a0.x + a0.y) + (a0.z + a0.w))
            + ((a1.x + a1.y) + (a1.z + a1.w))
            + ((a2.x + a2.y) + (a2.z + a2.w))
            + ((a3.x + a3.y) + (a3.z + a3.w));
#pragma unroll
    for (int off = 32; off > 0; off >>= 1)
        s += __shfl_down(s, off, 64);
    __shared__ float wsum[4];
    const int wid = tid >> 6, lane = tid & 63;
    if (lane == 0) wsum[wid] = s;
    __syncthreads();
    if (tid == 0) {
        const float total = (wsum[0] + wsum[1]) + (wsum[2] + wsum[3]);
        out[0] = 1.f - total * (float)(1.0 / TOTAL);
    }
}

extern "C" void kernel_launch(void* const* d_in, const int* in_sizes, int n_in,
                              void* d_out, int out_size, void* d_ws, size_t ws_size,
                              hipStream_t stream) {
    const float* P = (const float*)d_in[0];   // predict
    const float* G = (const float*)d_in[1];   // gt
    float* out = (float*)d_out;
    f16* wtab = (f16*)d_ws;                              // 1KB table
    float* blocksum = (float*)((char*)d_ws + 4096);      // NBLK floats

    init_kernel<<<1, 64, 0, stream>>>(wtab);
    ssim_mfma_kernel<<<NBLK, 256, 0, stream>>>(P, G, wtab, blocksum);
    reduce_kernel<<<1, 256, 0, stream>>>((const float4*)blocksum, out);
}